// Round 5
// baseline (25713.535 us; speedup 1.0000x reference)
//
#include <hip/hip_runtime.h>
#include <math.h>
#include <stdint.h>

// AIS estimator: N=1024 samples, B=128, DIM=DX=64, K=16 anneal steps, 3 leapfrog.
// Round 5: anti-spill restructure. Round 4 passed (absmax 0.0) but spilled
// ~2.8KB/thread (WRITE_SIZE 365MB, VALUBusy 32%). Now each trajectory is
// split across 4 lanes (16 dims each): per-thread state fits in ~80 VGPRs.
//  - q cross-lane sharing via padded LDS tile (2-way bank = free); A,W in LDS
//    (broadcast reads). 4 lanes/trajectory in one wave -> no barriers in loop.
//  - RNG: JAX partitionable threefry (out0^out1 of (0, idx)), verified round 4.
//  - gradient g = bk*((c - qA) - q) + (1-bk)*(mu - q), A = Wdec Wdec^T.
//  - final half-kick skipped: p fully resampled next step. p_noise input dead.

#define WS_A    0
#define WS_MU   4096
#define WS_C    12288
#define WS_SLW  20480
#define WS_TOTAL (WS_SLW + 131072)

struct KParams {
  float beta[18];
  float dbeta[17];
  uint32_t fk0[16];
  uint32_t fk1[16];
};

__host__ __device__ static inline void threefry2x32(uint32_t ks0, uint32_t ks1,
                                                    uint32_t x0, uint32_t x1,
                                                    uint32_t& o0, uint32_t& o1) {
  uint32_t ks2 = ks0 ^ ks1 ^ 0x1BD11BDAu;
  x0 += ks0; x1 += ks1;
#define TFR(r) { x0 += x1; x1 = (x1 << (r)) | (x1 >> (32 - (r))); x1 ^= x0; }
  TFR(13) TFR(15) TFR(26) TFR(6)
  x0 += ks1; x1 += ks2 + 1u;
  TFR(17) TFR(29) TFR(16) TFR(24)
  x0 += ks2; x1 += ks0 + 2u;
  TFR(13) TFR(15) TFR(26) TFR(6)
  x0 += ks0; x1 += ks1 + 3u;
  TFR(17) TFR(29) TFR(16) TFR(24)
  x0 += ks1; x1 += ks2 + 4u;
  TFR(13) TFR(15) TFR(26) TFR(6)
  x0 += ks2; x1 += ks0 + 5u;
#undef TFR
  o0 = x0; o1 = x1;
}

__device__ __forceinline__ float u_from_bits(uint32_t bits) {
  const float LO = __uint_as_float(0xBF7FFFFFu);  // nextafter(-1,0) in f32
  float f = __uint_as_float((bits >> 9) | 0x3F800000u) - 1.0f;
  float u = fmaf(f, 2.0f, LO);
  return fmaxf(LO, u);
}

// XLA ErfInv32 (Giles)
__device__ __forceinline__ float erfinv_f(float x) {
  float w = -log1pf(-x * x);
  float p;
  if (w < 5.0f) {
    w -= 2.5f;
    p = 2.81022636e-08f;
    p = fmaf(p, w, 3.43273939e-07f);
    p = fmaf(p, w, -3.5233877e-06f);
    p = fmaf(p, w, -4.39150654e-06f);
    p = fmaf(p, w, 0.00021858087f);
    p = fmaf(p, w, -0.00125372503f);
    p = fmaf(p, w, -0.00417768164f);
    p = fmaf(p, w, 0.246640727f);
    p = fmaf(p, w, 1.50140941f);
  } else {
    w = sqrtf(w) - 3.0f;
    p = -0.000200214257f;
    p = fmaf(p, w, 0.000100950558f);
    p = fmaf(p, w, 0.00134934322f);
    p = fmaf(p, w, -0.00367342844f);
    p = fmaf(p, w, 0.00573950773f);
    p = fmaf(p, w, -0.0076224613f);
    p = fmaf(p, w, 0.00943887047f);
    p = fmaf(p, w, 1.00167406f);
    p = fmaf(p, w, 2.83297682f);
  }
  return p * x;
}

// ---- setup: A = Wdec Wdec^T ; mu[b][d] = (x Wenc) ; c[b][d] = (x Wdec^T)
__global__ void k_setup1(const float* __restrict__ x, const float* __restrict__ Wenc,
                         const float* __restrict__ Wdec, float* __restrict__ ws) {
  int t = blockIdx.x * 256 + threadIdx.x;
  if (t < 4096) {
    int i = t >> 6, j = t & 63;
    float s = 0;
    for (int e = 0; e < 64; ++e) s = fmaf(Wdec[i*64+e], Wdec[j*64+e], s);
    ws[WS_A + t] = s;
  } else if (t < 12288) {
    int u = t - 4096; int b = u >> 6, d = u & 63;
    float s = 0;
    for (int e = 0; e < 64; ++e) s = fmaf(x[b*64+e], Wenc[e*64+d], s);
    ws[WS_MU + u] = s;
  } else if (t < 20480) {
    int u = t - 12288; int b = u >> 6, d = u & 63;
    float s = 0;
    for (int e = 0; e < 64; ++e) s = fmaf(x[b*64+e], Wdec[d*64+e], s);
    ws[WS_C + u] = s;
  }
}

// ---- main: 4 lanes per trajectory (16 dims each), 64 trajectories/block
__global__ __launch_bounds__(256, 3) void k_main(const float* __restrict__ qn,
                                                 const float* __restrict__ x,
                                                 const float* __restrict__ Wdec,
                                                 const float* __restrict__ ws,
                                                 float* __restrict__ slw_out,
                                                 KParams P) {
  __shared__ float As[4096];
  __shared__ float Wls[4096];
  __shared__ float qls[64 * 68];  // [traj][dim], pad 68 -> 2-way bank max
  const int tid = threadIdx.x;
  for (int i = tid; i < 4096; i += 256) {
    As[i]  = ws[WS_A + i];
    Wls[i] = Wdec[i];
  }
  __syncthreads();

  const int ltraj = tid >> 2, sub = tid & 3;
  const int gtraj = blockIdx.x * 64 + ltraj;
  const int b = gtraj & 127;
  const int d0 = sub * 16;
  float* qme = qls + ltraj * 68;

  // per-thread slices of mu, c (kept in regs; x read in w_eval, L1-resident)
  float mu[16], cc[16];
  {
    const float4* muP = (const float4*)(ws + WS_MU + b*64 + d0);
    const float4* cP  = (const float4*)(ws + WS_C  + b*64 + d0);
#pragma unroll
    for (int c4 = 0; c4 < 4; ++c4) {
      float4 m4 = muP[c4], v4 = cP[c4];
      mu[4*c4+0] = m4.x; mu[4*c4+1] = m4.y; mu[4*c4+2] = m4.z; mu[4*c4+3] = m4.w;
      cc[4*c4+0] = v4.x; cc[4*c4+1] = v4.y; cc[4*c4+2] = v4.z; cc[4*c4+3] = v4.w;
    }
  }

  float q[16], p[16], slw = 0.0f;

  // acc = (qvec * M)[d0 .. d0+16), qvec read from the trajectory's LDS tile
  auto matvec = [&](const float* M, float* acc) {
#pragma unroll
    for (int i = 0; i < 16; ++i) acc[i] = 0.0f;
#pragma unroll
    for (int m4 = 0; m4 < 16; ++m4) {
      float4 q4 = *(const float4*)(qme + 4*m4);
#pragma unroll
      for (int mm = 0; mm < 4; ++mm) {
        const float qm = (mm == 0) ? q4.x : (mm == 1) ? q4.y : (mm == 2) ? q4.z : q4.w;
        const float4* Mr = (const float4*)(M + (4*m4 + mm)*64 + d0);
#pragma unroll
        for (int c4 = 0; c4 < 4; ++c4) {
          float4 a = Mr[c4];
          acc[4*c4+0] = fmaf(qm, a.x, acc[4*c4+0]);
          acc[4*c4+1] = fmaf(qm, a.y, acc[4*c4+1]);
          acc[4*c4+2] = fmaf(qm, a.z, acc[4*c4+2]);
          acc[4*c4+3] = fmaf(qm, a.w, acc[4*c4+3]);
        }
      }
    }
  };

  auto kick = [&](float bk, bool dbl) {
    float acc[16];
    matvec(As, acc);
    const float omb = 1.0f - bk;
#pragma unroll
    for (int i = 0; i < 16; ++i) {
      float g = fmaf(bk, (cc[i] - acc[i]) - q[i], omb * (mu[i] - q[i]));
      p[i] = fmaf(0.025f, g, p[i]);                 // 0.5*STEP
      if (dbl) p[i] = fmaf(0.025f, g, p[i]);        // boundary double half-kick
    }
  };

  auto drift = [&]() {
#pragma unroll
    for (int i = 0; i < 16; ++i) q[i] = fmaf(0.05f, p[i], q[i]);
#pragma unroll
    for (int c4 = 0; c4 < 4; ++c4)
      *(float4*)(qme + d0 + 4*c4) = make_float4(q[4*c4], q[4*c4+1], q[4*c4+2], q[4*c4+3]);
  };

  auto w_eval = [&]() -> float {
    float r[16];
    matvec(Wls, r);
    float ssq = 0.0f;
    const float4* xP = (const float4*)(x + b*64 + d0);
#pragma unroll
    for (int c4 = 0; c4 < 4; ++c4) {
      float4 xv = xP[c4];
      float e0 = xv.x - r[4*c4+0]; ssq = fmaf(e0, e0, ssq);
      float e1 = xv.y - r[4*c4+1]; ssq = fmaf(e1, e1, ssq);
      float e2 = xv.z - r[4*c4+2]; ssq = fmaf(e2, e2, ssq);
      float e3 = xv.w - r[4*c4+3]; ssq = fmaf(e3, e3, ssq);
    }
    float s_q = 0.0f, s_qm = 0.0f;
#pragma unroll
    for (int i = 0; i < 16; ++i) {
      s_q = fmaf(q[i], q[i], s_q);
      float dm = q[i] - mu[i];
      s_qm = fmaf(dm, dm, s_qm);
    }
    float v = -0.5f * ssq - 0.5f * (s_q - s_qm);
    v += __shfl_xor(v, 1);
    v += __shfl_xor(v, 2);
    return v - 32.0f * 1.8378770664093453f;  // -0.5*64*log(2*pi)
  };

  // j = 0: q0 = mu + q_noise
  {
    const float4* qn4 = (const float4*)(qn + (size_t)gtraj*64 + d0);
#pragma unroll
    for (int c4 = 0; c4 < 4; ++c4) {
      float4 v = qn4[c4];
      q[4*c4+0] = mu[4*c4+0] + v.x;
      q[4*c4+1] = mu[4*c4+1] + v.y;
      q[4*c4+2] = mu[4*c4+2] + v.z;
      q[4*c4+3] = mu[4*c4+3] + v.w;
    }
#pragma unroll
    for (int c4 = 0; c4 < 4; ++c4)
      *(float4*)(qme + d0 + 4*c4) = make_float4(q[4*c4], q[4*c4+1], q[4*c4+2], q[4*c4+3]);
  }
  slw = fmaf(P.dbeta[0], w_eval(), slw);

  const uint32_t base = (uint32_t)gtraj * 64u + (uint32_t)d0;
  for (int j = 1; j <= 16; ++j) {
    const float bk = P.beta[j];
    const uint32_t k0 = P.fk0[j-1], k1 = P.fk1[j-1];
    // momentum refresh: partitionable threefry, counter (0, idx), bits = o0^o1
#pragma unroll 4
    for (int i = 0; i < 16; ++i) {
      uint32_t o0, o1;
      threefry2x32(k0, k1, 0u, base + (uint32_t)i, o0, o1);
      p[i] = 1.41421356f * erfinv_f(u_from_bits(o0 ^ o1));
    }
    kick(bk, false); drift();
    kick(bk, true);  drift();
    kick(bk, true);  drift();
    slw = fmaf(P.dbeta[j], w_eval(), slw);
  }
  if (sub == 0) slw_out[gtraj] = slw;
}

// ---- logsumexp over n per batch column b
__global__ void k_reduce(const float* __restrict__ slw, float* __restrict__ out) {
  __shared__ float red[256];
  int b = blockIdx.x, t = threadIdx.x;
  float v[4];
  float m = -INFINITY;
#pragma unroll
  for (int i = 0; i < 4; ++i) {
    v[i] = slw[(t + 256*i)*128 + b];
    m = fmaxf(m, v[i]);
  }
  red[t] = m; __syncthreads();
  for (int s = 128; s > 0; s >>= 1) {
    if (t < s) red[t] = fmaxf(red[t], red[t+s]);
    __syncthreads();
  }
  m = red[0]; __syncthreads();
  float sum = 0.0f;
#pragma unroll
  for (int i = 0; i < 4; ++i) sum += expf(v[i] - m);
  red[t] = sum; __syncthreads();
  for (int s = 128; s > 0; s >>= 1) {
    if (t < s) red[t] += red[t+s];
    __syncthreads();
  }
  if (t == 0) out[b] = m + logf(red[0]) - 6.93147180559945309f;  // - log(1024)
}

extern "C" void kernel_launch(void* const* d_in, const int* in_sizes, int n_in,
                              void* d_out, int out_size, void* d_ws, size_t ws_size,
                              hipStream_t stream) {
  const float* x    = (const float*)d_in[0];
  const float* Wenc = (const float*)d_in[1];
  const float* Wdec = (const float*)d_in[2];
  const float* qn   = (const float*)d_in[3];
  // d_in[4] (p_noise) is dead: momentum fully resampled every anneal step.
  float* ws  = (float*)d_ws;
  float* out = (float*)d_out;
  if (ws_size < (size_t)WS_TOTAL * sizeof(float)) return;

  KParams P;
  double bb[18];
  for (int i = 0; i < 18; ++i) {
    double tt = (double)i / 17.0;
    bb[i] = 1.0 / (1.0 + exp(-(8.0 * tt - 4.0)));
  }
  for (int i = 0; i < 18; ++i) P.beta[i] = (float)((bb[i] - bb[0]) / (bb[17] - bb[0]));
  for (int j = 0; j <= 16; ++j) P.dbeta[j] = P.beta[j+1] - P.beta[j];
  for (int k = 1; k <= 16; ++k) {
    uint32_t a, c;
    threefry2x32(0u, 42u, 0u, (uint32_t)k, a, c);  // fold_in(key(42), k)
    P.fk0[k-1] = a; P.fk1[k-1] = c;
  }

  hipLaunchKernelGGL(k_setup1, dim3(80), dim3(256), 0, stream, x, Wenc, Wdec, ws);
  hipLaunchKernelGGL(k_main, dim3(2048), dim3(256), 0, stream, qn, x, Wdec, ws, ws + WS_SLW, P);
  hipLaunchKernelGGL(k_reduce, dim3(128), dim3(256), 0, stream, ws + WS_SLW, out);
}

// Round 6
// 1796.511 us; speedup vs baseline: 14.3130x; 14.3130x over previous
//
#include <hip/hip_runtime.h>
#include <math.h>
#include <stdint.h>

// AIS estimator: N=1024 samples, B=128, DIM=DX=64, K=16 anneal steps, 3 leapfrog.
// Round 6: round 5's 4-lanes/trajectory layout, with the scratch bug fixed.
//  - Round 5's lambda `matvec(As, acc)` took the address of local arrays ->
//    compiler left acc/r in scratch -> 82 GB HBM traffic, VALUBusy 5.6%.
//    Fix: macro-ized matvec (textual inline); all arrays constant-indexed only.
//  - w_eval reformulated: ssq = |x|^2 - 2 c.q + q^T A q  (A = Wdec Wdec^T),
//    removing the W-matvec operand and Wls from LDS: LDS 50->34 KB, 4 blocks/CU.
//  - RNG: JAX partitionable threefry (bits = o0^o1 of (0, idx)), verified r4.
//  - final half-kick skipped: p fully resampled next step. p_noise input dead.

#define WS_A    0
#define WS_MU   4096
#define WS_C    12288
#define WS_XSQ  20480
#define WS_SLW  20608
#define WS_TOTAL (WS_SLW + 131072)

struct KParams {
  float beta[18];
  float dbeta[17];
  uint32_t fk0[16];
  uint32_t fk1[16];
};

__host__ __device__ static inline void threefry2x32(uint32_t ks0, uint32_t ks1,
                                                    uint32_t x0, uint32_t x1,
                                                    uint32_t& o0, uint32_t& o1) {
  uint32_t ks2 = ks0 ^ ks1 ^ 0x1BD11BDAu;
  x0 += ks0; x1 += ks1;
#define TFR(r) { x0 += x1; x1 = (x1 << (r)) | (x1 >> (32 - (r))); x1 ^= x0; }
  TFR(13) TFR(15) TFR(26) TFR(6)
  x0 += ks1; x1 += ks2 + 1u;
  TFR(17) TFR(29) TFR(16) TFR(24)
  x0 += ks2; x1 += ks0 + 2u;
  TFR(13) TFR(15) TFR(26) TFR(6)
  x0 += ks0; x1 += ks1 + 3u;
  TFR(17) TFR(29) TFR(16) TFR(24)
  x0 += ks1; x1 += ks2 + 4u;
  TFR(13) TFR(15) TFR(26) TFR(6)
  x0 += ks2; x1 += ks0 + 5u;
#undef TFR
  o0 = x0; o1 = x1;
}

__device__ __forceinline__ float u_from_bits(uint32_t bits) {
  const float LO = __uint_as_float(0xBF7FFFFFu);  // nextafter(-1,0) in f32
  float f = __uint_as_float((bits >> 9) | 0x3F800000u) - 1.0f;
  float u = fmaf(f, 2.0f, LO);
  return fmaxf(LO, u);
}

// XLA ErfInv32 (Giles)
__device__ __forceinline__ float erfinv_f(float x) {
  float w = -log1pf(-x * x);
  float p;
  if (w < 5.0f) {
    w -= 2.5f;
    p = 2.81022636e-08f;
    p = fmaf(p, w, 3.43273939e-07f);
    p = fmaf(p, w, -3.5233877e-06f);
    p = fmaf(p, w, -4.39150654e-06f);
    p = fmaf(p, w, 0.00021858087f);
    p = fmaf(p, w, -0.00125372503f);
    p = fmaf(p, w, -0.00417768164f);
    p = fmaf(p, w, 0.246640727f);
    p = fmaf(p, w, 1.50140941f);
  } else {
    w = sqrtf(w) - 3.0f;
    p = -0.000200214257f;
    p = fmaf(p, w, 0.000100950558f);
    p = fmaf(p, w, 0.00134934322f);
    p = fmaf(p, w, -0.00367342844f);
    p = fmaf(p, w, 0.00573950773f);
    p = fmaf(p, w, -0.0076224613f);
    p = fmaf(p, w, 0.00943887047f);
    p = fmaf(p, w, 1.00167406f);
    p = fmaf(p, w, 2.83297682f);
  }
  return p * x;
}

// ---- setup: A = Wdec Wdec^T ; mu[b][d] = x Wenc ; c[b][d] = x Wdec^T ; xsq[b]
__global__ void k_setup1(const float* __restrict__ x, const float* __restrict__ Wenc,
                         const float* __restrict__ Wdec, float* __restrict__ ws) {
  int t = blockIdx.x * 256 + threadIdx.x;
  if (t < 4096) {
    int i = t >> 6, j = t & 63;
    float s = 0;
    for (int e = 0; e < 64; ++e) s = fmaf(Wdec[i*64+e], Wdec[j*64+e], s);
    ws[WS_A + t] = s;
  } else if (t < 12288) {
    int u = t - 4096; int b = u >> 6, d = u & 63;
    float s = 0;
    for (int e = 0; e < 64; ++e) s = fmaf(x[b*64+e], Wenc[e*64+d], s);
    ws[WS_MU + u] = s;
  } else if (t < 20480) {
    int u = t - 12288; int b = u >> 6, d = u & 63;
    float s = 0;
    for (int e = 0; e < 64; ++e) s = fmaf(x[b*64+e], Wdec[d*64+e], s);
    ws[WS_C + u] = s;
  } else if (t < 20608) {
    int b = t - 20480;
    float s = 0;
    for (int e = 0; e < 64; ++e) s = fmaf(x[b*64+e], x[b*64+e], s);
    ws[WS_XSQ + b] = s;
  }
}

// acc[i] = sum_m q[m] * A[m][d0+i], m ascending (matches validated order).
// Macro (not function/lambda): no address-taking -> arrays stay in VGPRs.
#define MATVEC_A(ACC)                                                        \
  do {                                                                       \
    _Pragma("unroll")                                                        \
    for (int i = 0; i < 16; ++i) ACC[i] = 0.0f;                              \
    _Pragma("unroll 4")                                                      \
    for (int m4 = 0; m4 < 16; ++m4) {                                        \
      float4 q4 = *(const float4*)(qme + 4 * m4);                            \
      const float4* r0 = (const float4*)(As + (4*m4+0)*64 + d0);             \
      const float4* r1 = (const float4*)(As + (4*m4+1)*64 + d0);             \
      const float4* r2 = (const float4*)(As + (4*m4+2)*64 + d0);             \
      const float4* r3 = (const float4*)(As + (4*m4+3)*64 + d0);             \
      _Pragma("unroll")                                                      \
      for (int c4 = 0; c4 < 4; ++c4) {                                       \
        float4 a0 = r0[c4], a1 = r1[c4], a2 = r2[c4], a3 = r3[c4];           \
        ACC[4*c4+0] = fmaf(q4.x, a0.x, ACC[4*c4+0]);                         \
        ACC[4*c4+0] = fmaf(q4.y, a1.x, ACC[4*c4+0]);                         \
        ACC[4*c4+0] = fmaf(q4.z, a2.x, ACC[4*c4+0]);                         \
        ACC[4*c4+0] = fmaf(q4.w, a3.x, ACC[4*c4+0]);                         \
        ACC[4*c4+1] = fmaf(q4.x, a0.y, ACC[4*c4+1]);                         \
        ACC[4*c4+1] = fmaf(q4.y, a1.y, ACC[4*c4+1]);                         \
        ACC[4*c4+1] = fmaf(q4.z, a2.y, ACC[4*c4+1]);                         \
        ACC[4*c4+1] = fmaf(q4.w, a3.y, ACC[4*c4+1]);                         \
        ACC[4*c4+2] = fmaf(q4.x, a0.z, ACC[4*c4+2]);                         \
        ACC[4*c4+2] = fmaf(q4.y, a1.z, ACC[4*c4+2]);                         \
        ACC[4*c4+2] = fmaf(q4.z, a2.z, ACC[4*c4+2]);                         \
        ACC[4*c4+2] = fmaf(q4.w, a3.z, ACC[4*c4+2]);                         \
        ACC[4*c4+3] = fmaf(q4.x, a0.w, ACC[4*c4+3]);                         \
        ACC[4*c4+3] = fmaf(q4.y, a1.w, ACC[4*c4+3]);                         \
        ACC[4*c4+3] = fmaf(q4.z, a2.w, ACC[4*c4+3]);                         \
        ACC[4*c4+3] = fmaf(q4.w, a3.w, ACC[4*c4+3]);                         \
      }                                                                      \
    }                                                                        \
  } while (0)

// w partial from current q (uses acc = qA): per-lane part, then quad-reduce.
#define W_EVAL(WOUT)                                                         \
  do {                                                                       \
    float acc[16];                                                           \
    MATVEC_A(acc);                                                           \
    float cq = 0.0f, qaq = 0.0f, s_q = 0.0f, s_qm = 0.0f;                    \
    _Pragma("unroll")                                                        \
    for (int i = 0; i < 16; ++i) {                                           \
      cq  = fmaf(cc[i], q[i], cq);                                           \
      qaq = fmaf(q[i], acc[i], qaq);                                         \
      s_q = fmaf(q[i], q[i], s_q);                                           \
      float dm = q[i] - mu[i];                                               \
      s_qm = fmaf(dm, dm, s_qm);                                             \
    }                                                                        \
    float v = cq - 0.5f * qaq - 0.5f * (s_q - s_qm);                         \
    v += __shfl_xor(v, 1);                                                   \
    v += __shfl_xor(v, 2);                                                   \
    WOUT = v - 0.5f * xsq - 32.0f * 1.8378770664093453f;                     \
  } while (0)

// ---- main: 4 lanes per trajectory (16 dims each), 64 trajectories/block
__global__ __launch_bounds__(256, 4) void k_main(const float* __restrict__ qn,
                                                 const float* __restrict__ ws,
                                                 float* __restrict__ slw_out,
                                                 KParams P) {
  __shared__ float As[4096];
  __shared__ float qls[64 * 68];  // [traj][dim], pad 68 -> 2-way bank max (free)
  const int tid = threadIdx.x;
  for (int i = tid; i < 4096; i += 256) As[i] = ws[WS_A + i];
  __syncthreads();

  const int ltraj = tid >> 2, sub = tid & 3;
  const int gtraj = blockIdx.x * 64 + ltraj;
  const int b = gtraj & 127;
  const int d0 = sub * 16;
  float* qme = qls + ltraj * 68;
  const float xsq = ws[WS_XSQ + b];

  float mu[16], cc[16];
  {
    const float4* muP = (const float4*)(ws + WS_MU + b*64 + d0);
    const float4* cP  = (const float4*)(ws + WS_C  + b*64 + d0);
#pragma unroll
    for (int c4 = 0; c4 < 4; ++c4) {
      float4 m4 = muP[c4], v4 = cP[c4];
      mu[4*c4+0] = m4.x; mu[4*c4+1] = m4.y; mu[4*c4+2] = m4.z; mu[4*c4+3] = m4.w;
      cc[4*c4+0] = v4.x; cc[4*c4+1] = v4.y; cc[4*c4+2] = v4.z; cc[4*c4+3] = v4.w;
    }
  }

  float q[16], p[16], slw = 0.0f;

  // j = 0: q0 = mu + q_noise
  {
    const float4* qn4 = (const float4*)(qn + (size_t)gtraj*64 + d0);
#pragma unroll
    for (int c4 = 0; c4 < 4; ++c4) {
      float4 v = qn4[c4];
      q[4*c4+0] = mu[4*c4+0] + v.x;
      q[4*c4+1] = mu[4*c4+1] + v.y;
      q[4*c4+2] = mu[4*c4+2] + v.z;
      q[4*c4+3] = mu[4*c4+3] + v.w;
    }
#pragma unroll
    for (int c4 = 0; c4 < 4; ++c4)
      *(float4*)(qme + d0 + 4*c4) = make_float4(q[4*c4], q[4*c4+1], q[4*c4+2], q[4*c4+3]);
  }
  {
    float w0;
    W_EVAL(w0);
    slw = fmaf(P.dbeta[0], w0, slw);
  }

  const uint32_t base = (uint32_t)gtraj * 64u + (uint32_t)d0;
  for (int j = 1; j <= 16; ++j) {
    const float bk = P.beta[j];
    const float omb = 1.0f - bk;
    const uint32_t k0 = P.fk0[j-1], k1 = P.fk1[j-1];
    // momentum refresh: partitionable threefry, counter (0, idx), bits = o0^o1
#pragma unroll
    for (int i = 0; i < 16; ++i) {
      uint32_t o0, o1;
      threefry2x32(k0, k1, 0u, base + (uint32_t)i, o0, o1);
      p[i] = 1.41421356f * erfinv_f(u_from_bits(o0 ^ o1));
    }
    // 3 leapfrog steps: kick(h/2) [s=0 single, s>0 doubled boundary], drift
    for (int s = 0; s < 3; ++s) {
      float acc[16];
      MATVEC_A(acc);
#pragma unroll
      for (int i = 0; i < 16; ++i) {
        float g = fmaf(bk, (cc[i] - acc[i]) - q[i], omb * (mu[i] - q[i]));
        p[i] = fmaf(0.025f, g, p[i]);
        if (s > 0) p[i] = fmaf(0.025f, g, p[i]);
      }
#pragma unroll
      for (int i = 0; i < 16; ++i) q[i] = fmaf(0.05f, p[i], q[i]);
#pragma unroll
      for (int c4 = 0; c4 < 4; ++c4)
        *(float4*)(qme + d0 + 4*c4) = make_float4(q[4*c4], q[4*c4+1], q[4*c4+2], q[4*c4+3]);
    }
    float wj;
    W_EVAL(wj);
    slw = fmaf(P.dbeta[j], wj, slw);
  }
  if (sub == 0) slw_out[gtraj] = slw;
}

// ---- logsumexp over n per batch column b
__global__ void k_reduce(const float* __restrict__ slw, float* __restrict__ out) {
  __shared__ float red[256];
  int b = blockIdx.x, t = threadIdx.x;
  float v[4];
  float m = -INFINITY;
#pragma unroll
  for (int i = 0; i < 4; ++i) {
    v[i] = slw[(t + 256*i)*128 + b];
    m = fmaxf(m, v[i]);
  }
  red[t] = m; __syncthreads();
  for (int s = 128; s > 0; s >>= 1) {
    if (t < s) red[t] = fmaxf(red[t], red[t+s]);
    __syncthreads();
  }
  m = red[0]; __syncthreads();
  float sum = 0.0f;
#pragma unroll
  for (int i = 0; i < 4; ++i) sum += expf(v[i] - m);
  red[t] = sum; __syncthreads();
  for (int s = 128; s > 0; s >>= 1) {
    if (t < s) red[t] += red[t+s];
    __syncthreads();
  }
  if (t == 0) out[b] = m + logf(red[0]) - 6.93147180559945309f;  // - log(1024)
}

extern "C" void kernel_launch(void* const* d_in, const int* in_sizes, int n_in,
                              void* d_out, int out_size, void* d_ws, size_t ws_size,
                              hipStream_t stream) {
  const float* x    = (const float*)d_in[0];
  const float* Wenc = (const float*)d_in[1];
  const float* Wdec = (const float*)d_in[2];
  const float* qn   = (const float*)d_in[3];
  // d_in[4] (p_noise) is dead: momentum fully resampled every anneal step.
  float* ws  = (float*)d_ws;
  float* out = (float*)d_out;
  if (ws_size < (size_t)WS_TOTAL * sizeof(float)) return;

  KParams P;
  double bb[18];
  for (int i = 0; i < 18; ++i) {
    double tt = (double)i / 17.0;
    bb[i] = 1.0 / (1.0 + exp(-(8.0 * tt - 4.0)));
  }
  for (int i = 0; i < 18; ++i) P.beta[i] = (float)((bb[i] - bb[0]) / (bb[17] - bb[0]));
  for (int j = 0; j <= 16; ++j) P.dbeta[j] = P.beta[j+1] - P.beta[j];
  for (int k = 1; k <= 16; ++k) {
    uint32_t a, c;
    threefry2x32(0u, 42u, 0u, (uint32_t)k, a, c);  // fold_in(key(42), k)
    P.fk0[k-1] = a; P.fk1[k-1] = c;
  }

  hipLaunchKernelGGL(k_setup1, dim3(81), dim3(256), 0, stream, x, Wenc, Wdec, ws);
  hipLaunchKernelGGL(k_main, dim3(2048), dim3(256), 0, stream, qn, ws, ws + WS_SLW, P);
  hipLaunchKernelGGL(k_reduce, dim3(128), dim3(256), 0, stream, ws + WS_SLW, out);
}